// Round 1
// baseline (351.368 us; speedup 1.0000x reference)
//
#include <hip/hip_runtime.h>

// B=8, C=d=128, H=W=64, N=H*W=4096
#define NB 8
#define CD 128
#define NN 4096
#define SCALE 0.08838834764831845f
#define L2E 1.44269504088896f

typedef __bf16 bf16x8 __attribute__((ext_vector_type(8)));
typedef float f32x4 __attribute__((ext_vector_type(4)));

// XOR swizzles on 16B blocks within a row; involution -> same fn for write & read.
__device__ __forceinline__ unsigned swz256(unsigned row, unsigned b) {
  unsigned s = b >> 4, o = b & 15u;
  unsigned sw = (s & 8u) | ((s & 7u) ^ (row & 7u));
  return row * 256u + sw * 16u + o;
}
__device__ __forceinline__ unsigned swz128(unsigned row, unsigned b) {
  unsigned s = b >> 4, o = b & 15u;
  unsigned sw = (s ^ row) & 7u;
  return row * 128u + sw * 16u + o;
}

// ---------------------------------------------------------------------------
// Kernel 1: fused transpose + QKV projection.
//  Q,K computed in split bf16 (3 MFMAs: hh+hl+lh) for ~fp32 logit accuracy.
//  Outputs: Qh/Ql (Q*scale, hi/lo), Kh/Kl, Vt (V transposed to [b][d][n]).
// ---------------------------------------------------------------------------
__global__ __launch_bounds__(256, 2) void qkv_kernel(
    const float* __restrict__ x,
    const float* __restrict__ qw, const float* __restrict__ qb,
    const float* __restrict__ kw, const float* __restrict__ kb,
    const float* __restrict__ vw, const float* __restrict__ vb,
    __bf16* __restrict__ Qh, __bf16* __restrict__ Ql,
    __bf16* __restrict__ Kh, __bf16* __restrict__ Kl,
    __bf16* __restrict__ Vt)
{
  // xh:[0,16384) xl:[16384,32768) wt_h:[32768,40960) wt_l:[40960,49152)
  // vtmp (bf16 [64][132]) aliases wt: [32768, 49664)
  __shared__ __align__(16) unsigned char sm[49664];
  const int tid = threadIdx.x;
  const int lane = tid & 63, wv = tid >> 6;
  const int l15 = lane & 15, g = lane >> 4;
  const int b = blockIdx.y;
  const int n0 = blockIdx.x * 64;
  const f32x4 Z4 = {0.f, 0.f, 0.f, 0.f};

  // stage x tile transposed -> xt[n][c], split hi/lo
  #pragma unroll 4
  for (int i = 0; i < 32; ++i) {
    int e = i * 256 + tid;
    int nl = e & 63, c = e >> 6;
    float f = x[((size_t)(b * CD + c)) * NN + n0 + nl];
    __bf16 h = (__bf16)f;
    __bf16 lo = (__bf16)(f - (float)h);
    unsigned off = swz256((unsigned)nl, (unsigned)(c * 2));
    *(__bf16*)(sm + off) = h;
    *(__bf16*)(sm + 16384 + off) = lo;
  }
  __syncthreads();

  // hoist A fragments (this wave's 16 rows, full K=128)
  bf16x8 ah[4], al[4];
  #pragma unroll
  for (int kk = 0; kk < 4; ++kk) {
    unsigned off = swz256((unsigned)(wv * 16 + l15), (unsigned)(kk * 64 + g * 16));
    ah[kk] = *(const bf16x8*)(sm + off);
    al[kk] = *(const bf16x8*)(sm + 16384 + off);
  }

  // Q then K, split precision, quarter tiles of douts (32 at a time)
  for (int mat = 0; mat < 2; ++mat) {
    const float* gw = mat ? kw : qw;
    const float* gb = mat ? kb : qb;
    __bf16* Oh = mat ? Kh : Qh;
    __bf16* Ol = mat ? Kl : Ql;
    const float sc = mat ? 1.0f : SCALE;
    for (int qd = 0; qd < 4; ++qd) {
      #pragma unroll 4
      for (int i = 0; i < 16; ++i) {  // stage wT quarter [32 dout][128 c] hi/lo
        int e = i * 256 + tid;
        int dl = e & 31, c = e >> 5;
        float f = gw[c * CD + qd * 32 + dl];
        __bf16 h = (__bf16)f;
        __bf16 lo = (__bf16)(f - (float)h);
        unsigned off = swz256((unsigned)dl, (unsigned)(c * 2));
        *(__bf16*)(sm + 32768 + off) = h;
        *(__bf16*)(sm + 40960 + off) = lo;
      }
      __syncthreads();
      #pragma unroll
      for (int fr = 0; fr < 2; ++fr) {
        f32x4 acc = Z4;
        #pragma unroll
        for (int kk = 0; kk < 4; ++kk) {
          unsigned off = swz256((unsigned)(fr * 16 + l15), (unsigned)(kk * 64 + g * 16));
          bf16x8 bh = *(const bf16x8*)(sm + 32768 + off);
          bf16x8 bl = *(const bf16x8*)(sm + 40960 + off);
          acc = __builtin_amdgcn_mfma_f32_16x16x32_bf16(ah[kk], bh, acc, 0, 0, 0);
          acc = __builtin_amdgcn_mfma_f32_16x16x32_bf16(ah[kk], bl, acc, 0, 0, 0);
          acc = __builtin_amdgcn_mfma_f32_16x16x32_bf16(al[kk], bh, acc, 0, 0, 0);
        }
        const int dout = qd * 32 + fr * 16 + l15;
        const float bias = gb[dout];
        #pragma unroll
        for (int r = 0; r < 4; ++r) {
          int row = n0 + wv * 16 + g * 4 + r;
          float v = (acc[r] + bias) * sc;
          __bf16 h = (__bf16)v;
          __bf16 lo = (__bf16)(v - (float)h);
          size_t go = ((size_t)(b * NN + row)) * CD + dout;
          Oh[go] = h;
          Ol[go] = lo;
        }
      }
      __syncthreads();
    }
  }

  // V: plain bf16, accumulate all 128 douts, then transpose out via LDS
  f32x4 accV[8];
  #pragma unroll
  for (int i = 0; i < 8; ++i) accV[i] = Z4;
  for (int qd = 0; qd < 4; ++qd) {
    #pragma unroll 4
    for (int i = 0; i < 16; ++i) {
      int e = i * 256 + tid;
      int dl = e & 31, c = e >> 5;
      float f = vw[c * CD + qd * 32 + dl];
      *(__bf16*)(sm + 32768 + swz256((unsigned)dl, (unsigned)(c * 2))) = (__bf16)f;
    }
    __syncthreads();
    #pragma unroll
    for (int fr = 0; fr < 2; ++fr) {
      f32x4 acc = accV[qd * 2 + fr];
      #pragma unroll
      for (int kk = 0; kk < 4; ++kk) {
        unsigned off = swz256((unsigned)(fr * 16 + l15), (unsigned)(kk * 64 + g * 16));
        bf16x8 bh = *(const bf16x8*)(sm + 32768 + off);
        acc = __builtin_amdgcn_mfma_f32_16x16x32_bf16(ah[kk], bh, acc, 0, 0, 0);
      }
      accV[qd * 2 + fr] = acc;
    }
    __syncthreads();
  }
  // write V tile to vtmp[64][132] bf16 (aliases wt region; sync'd above)
  #pragma unroll
  for (int df = 0; df < 8; ++df) {
    int dout = df * 16 + l15;
    float bias = vb[dout];
    #pragma unroll
    for (int r = 0; r < 4; ++r) {
      int row = wv * 16 + g * 4 + r;
      *(__bf16*)(sm + 32768 + (row * 132 + dout) * 2) = (__bf16)(accV[df][r] + bias);
    }
  }
  __syncthreads();
  #pragma unroll 4
  for (int i = 0; i < 32; ++i) {
    int e = i * 256 + tid;
    int nl = e & 63, dout = e >> 6;
    __bf16 v = *(const __bf16*)(sm + 32768 + (nl * 132 + dout) * 2);
    Vt[((size_t)(b * CD + dout)) * NN + n0 + nl] = v;
  }
}

// ---------------------------------------------------------------------------
// Kernel 2: flash attention (64 q-rows/block, KV tiles of 64) + fused
//  output projection + bias + residual.  QK^T in split bf16 (3 MFMAs).
// ---------------------------------------------------------------------------
__global__ __launch_bounds__(256, 2) void attn_kernel(
    const __bf16* __restrict__ Qh, const __bf16* __restrict__ Ql,
    const __bf16* __restrict__ Kh, const __bf16* __restrict__ Kl,
    const __bf16* __restrict__ Vt, const float* __restrict__ x,
    const float* __restrict__ pw, const float* __restrict__ pb,
    float* __restrict__ out)
{
  // loop:     KH:[0,16384) KL:[16384,32768) VT:[32768,49152) P:[49152,57344)
  // epilogue: O:[0,16384)  PWT:[16384,49152)   (aliases loop bufs after sync)
  __shared__ __align__(16) unsigned char sm[57344];
  const int tid = threadIdx.x;
  const int lane = tid & 63, wv = tid >> 6;
  const int l15 = lane & 15, g = lane >> 4;
  const int b = blockIdx.y;
  const int q0 = blockIdx.x * 64;
  const f32x4 Z4 = {0.f, 0.f, 0.f, 0.f};

  // Q fragments (hi/lo) straight from global into registers
  bf16x8 qh[4], ql[4];
  #pragma unroll
  for (int kk = 0; kk < 4; ++kk) {
    size_t off = ((size_t)(b * NN + q0 + wv * 16 + l15)) * CD + kk * 32 + g * 8;
    qh[kk] = *(const bf16x8*)(Qh + off);
    ql[kk] = *(const bf16x8*)(Ql + off);
  }

  f32x4 accO[8];
  #pragma unroll
  for (int i = 0; i < 8; ++i) accO[i] = Z4;
  float mrow[4], lrow[4];
  #pragma unroll
  for (int r = 0; r < 4; ++r) { mrow[r] = -__builtin_inff(); lrow[r] = 0.f; }

  for (int kt = 0; kt < 64; ++kt) {
    // stage K (hi/lo, [64 key][128 c]) and V^T ([128 d][64 key]) tiles
    const int kbase = b * NN + kt * 64;
    #pragma unroll
    for (int i = 0; i < 4; ++i) {
      int id = i * 256 + tid;
      int r = id >> 4, s = id & 15;
      size_t go = ((size_t)(kbase + r)) * CD + s * 8;
      unsigned off = swz256((unsigned)r, (unsigned)(s * 16));
      *(bf16x8*)(sm + off) = *(const bf16x8*)(Kh + go);
      *(bf16x8*)(sm + 16384 + off) = *(const bf16x8*)(Kl + go);
      int r2 = id >> 3, s2 = id & 7;
      *(bf16x8*)(sm + 32768 + swz128((unsigned)r2, (unsigned)(s2 * 16))) =
          *(const bf16x8*)(Vt + ((size_t)(b * CD + r2)) * NN + kt * 64 + s2 * 8);
    }
    __syncthreads();

    // S = Qs * K^T  (split: hh + hl + lh)
    f32x4 s4[4];
    #pragma unroll
    for (int kf = 0; kf < 4; ++kf) s4[kf] = Z4;
    #pragma unroll
    for (int kf = 0; kf < 4; ++kf) {
      #pragma unroll
      for (int kk = 0; kk < 4; ++kk) {
        unsigned off = swz256((unsigned)(kf * 16 + l15), (unsigned)(kk * 64 + g * 16));
        bf16x8 bh = *(const bf16x8*)(sm + off);
        bf16x8 bl = *(const bf16x8*)(sm + 16384 + off);
        s4[kf] = __builtin_amdgcn_mfma_f32_16x16x32_bf16(qh[kk], bh, s4[kf], 0, 0, 0);
        s4[kf] = __builtin_amdgcn_mfma_f32_16x16x32_bf16(qh[kk], bl, s4[kf], 0, 0, 0);
        s4[kf] = __builtin_amdgcn_mfma_f32_16x16x32_bf16(ql[kk], bh, s4[kf], 0, 0, 0);
      }
    }

    // online softmax (rows live in 16-lane groups; shfl_xor 1,2,4,8)
    float alpha[4];
    #pragma unroll
    for (int r = 0; r < 4; ++r) {
      float mx = fmaxf(fmaxf(s4[0][r], s4[1][r]), fmaxf(s4[2][r], s4[3][r]));
      mx = fmaxf(mx, __shfl_xor(mx, 1));
      mx = fmaxf(mx, __shfl_xor(mx, 2));
      mx = fmaxf(mx, __shfl_xor(mx, 4));
      mx = fmaxf(mx, __shfl_xor(mx, 8));
      float mn = fmaxf(mrow[r], mx);
      alpha[r] = exp2f((mrow[r] - mn) * L2E);
      mrow[r] = mn;
      float ps = 0.f;
      #pragma unroll
      for (int kf = 0; kf < 4; ++kf) {
        float p = exp2f((s4[kf][r] - mn) * L2E);
        s4[kf][r] = p;
        ps += p;
      }
      ps += __shfl_xor(ps, 1);
      ps += __shfl_xor(ps, 2);
      ps += __shfl_xor(ps, 4);
      ps += __shfl_xor(ps, 8);
      lrow[r] = lrow[r] * alpha[r] + ps;
    }

    // write P (bf16) to this wave's private LDS rows (no block sync needed)
    #pragma unroll
    for (int kf = 0; kf < 4; ++kf) {
      #pragma unroll
      for (int r = 0; r < 4; ++r) {
        unsigned row = (unsigned)(wv * 16 + g * 4 + r);
        *(__bf16*)(sm + 49152 + swz128(row, (unsigned)((kf * 16 + l15) * 2))) =
            (__bf16)s4[kf][r];
      }
    }
    // rescale O
    #pragma unroll
    for (int df = 0; df < 8; ++df) {
      #pragma unroll
      for (int r = 0; r < 4; ++r) accO[df][r] *= alpha[r];
    }
    // O += P * V
    bf16x8 pa[2];
    #pragma unroll
    for (int kk2 = 0; kk2 < 2; ++kk2)
      pa[kk2] = *(const bf16x8*)(sm + 49152 +
                  swz128((unsigned)(wv * 16 + l15), (unsigned)(kk2 * 64 + g * 16)));
    #pragma unroll
    for (int df = 0; df < 8; ++df) {
      #pragma unroll
      for (int kk2 = 0; kk2 < 2; ++kk2) {
        bf16x8 bv = *(const bf16x8*)(sm + 32768 +
                      swz128((unsigned)(df * 16 + l15), (unsigned)(kk2 * 64 + g * 16)));
        accO[df] = __builtin_amdgcn_mfma_f32_16x16x32_bf16(pa[kk2], bv, accO[df], 0, 0, 0);
      }
    }
    __syncthreads();
  }

  // epilogue: O/l -> bf16 LDS, stage proj_w^T, hout = O @ pw + pb + residual
  float rl[4];
  #pragma unroll
  for (int r = 0; r < 4; ++r) rl[r] = 1.0f / lrow[r];
  #pragma unroll
  for (int df = 0; df < 8; ++df) {
    #pragma unroll
    for (int r = 0; r < 4; ++r) {
      unsigned row = (unsigned)(wv * 16 + g * 4 + r);
      *(__bf16*)(sm + swz256(row, (unsigned)((df * 16 + l15) * 2))) =
          (__bf16)(accO[df][r] * rl[r]);
    }
  }
  #pragma unroll 4
  for (int i = 0; i < 16; ++i) {  // pwT[dout][c] bf16 at 16384
    int e = i * 256 + tid;
    int c = e >> 5, d4 = e & 31;
    const float4 w4 = *(const float4*)(pw + c * CD + d4 * 4);
    *(__bf16*)(sm + 16384 + swz256((unsigned)(d4 * 4 + 0), (unsigned)(c * 2))) = (__bf16)w4.x;
    *(__bf16*)(sm + 16384 + swz256((unsigned)(d4 * 4 + 1), (unsigned)(c * 2))) = (__bf16)w4.y;
    *(__bf16*)(sm + 16384 + swz256((unsigned)(d4 * 4 + 2), (unsigned)(c * 2))) = (__bf16)w4.z;
    *(__bf16*)(sm + 16384 + swz256((unsigned)(d4 * 4 + 3), (unsigned)(c * 2))) = (__bf16)w4.w;
  }
  __syncthreads();

  bf16x8 oa[4];
  #pragma unroll
  for (int kk = 0; kk < 4; ++kk)
    oa[kk] = *(const bf16x8*)(sm + swz256((unsigned)(wv * 16 + l15),
                                          (unsigned)(kk * 64 + g * 16)));
  #pragma unroll
  for (int df = 0; df < 8; ++df) {
    f32x4 acc = Z4;
    #pragma unroll
    for (int kk = 0; kk < 4; ++kk) {
      bf16x8 bw = *(const bf16x8*)(sm + 16384 +
                    swz256((unsigned)(df * 16 + l15), (unsigned)(kk * 64 + g * 16)));
      acc = __builtin_amdgcn_mfma_f32_16x16x32_bf16(oa[kk], bw, acc, 0, 0, 0);
    }
    const int cc = df * 16 + l15;
    const float bias = pb[cc];
    #pragma unroll
    for (int r = 0; r < 4; ++r) {
      int row = q0 + wv * 16 + g * 4 + r;
      float val = acc[r] + bias + x[((size_t)(b * CD + cc)) * NN + row];
      out[((size_t)(b * NN + row)) * CD + cc] = val;
    }
  }
}

// ---------------------------------------------------------------------------
extern "C" void kernel_launch(void* const* d_in, const int* in_sizes, int n_in,
                              void* d_out, int out_size, void* d_ws, size_t ws_size,
                              hipStream_t stream) {
  (void)in_sizes; (void)n_in; (void)out_size; (void)ws_size;
  const float* x  = (const float*)d_in[0];
  const float* qw = (const float*)d_in[1];
  const float* qb = (const float*)d_in[2];
  const float* kw = (const float*)d_in[3];
  const float* kb = (const float*)d_in[4];
  const float* vw = (const float*)d_in[5];
  const float* vb = (const float*)d_in[6];
  const float* pw = (const float*)d_in[7];
  const float* pb = (const float*)d_in[8];
  float* out = (float*)d_out;

  const size_t SZ = (size_t)NB * NN * CD;  // 4.19M elems per buffer
  __bf16* Qh = (__bf16*)d_ws;              // ws usage: 5 * 8.39 MB = 41.9 MB
  __bf16* Ql = Qh + SZ;
  __bf16* Kh = Ql + SZ;
  __bf16* Kl = Kh + SZ;
  __bf16* Vt = Kl + SZ;

  dim3 grid(NN / 64, NB), blk(256);
  qkv_kernel<<<grid, blk, 0, stream>>>(x, qw, qb, kw, kb, vw, vb,
                                       Qh, Ql, Kh, Kl, Vt);
  attn_kernel<<<grid, blk, 0, stream>>>(Qh, Ql, Kh, Kl, Vt, x, pw, pb, out);
}

// Round 2
// 344.638 us; speedup vs baseline: 1.0195x; 1.0195x over previous
//
#include <hip/hip_runtime.h>

// B=8, C=d=128, H=W=64, N=H*W=4096
#define NB 8
#define CD 128
#define NN 4096
#define SCALE 0.08838834764831845f
#define L2E 1.44269504088896f

typedef __bf16 bf16x8 __attribute__((ext_vector_type(8)));
typedef float f32x4 __attribute__((ext_vector_type(4)));

// XOR swizzles on 16B blocks within a row; involution -> same fn for write & read.
__device__ __forceinline__ unsigned swz256(unsigned row, unsigned b) {
  unsigned s = b >> 4, o = b & 15u;
  unsigned sw = (s & 8u) | ((s & 7u) ^ (row & 7u));
  return row * 256u + sw * 16u + o;
}
__device__ __forceinline__ unsigned swz128(unsigned row, unsigned b) {
  unsigned s = b >> 4, o = b & 15u;
  unsigned sw = (s ^ row) & 7u;
  return row * 128u + sw * 16u + o;
}

// ---------------------------------------------------------------------------
// Kernel 1: fused transpose + QKV projection.
//  Q,K computed in split bf16 (3 MFMAs: hh+hl+lh) for ~fp32 logit accuracy.
//  Outputs: Qh/Ql (Q*scale, hi/lo), Kh/Kl, Vt (V transposed to [b][d][n]).
// ---------------------------------------------------------------------------
__global__ __launch_bounds__(256, 2) void qkv_kernel(
    const float* __restrict__ x,
    const float* __restrict__ qw, const float* __restrict__ qb,
    const float* __restrict__ kw, const float* __restrict__ kb,
    const float* __restrict__ vw, const float* __restrict__ vb,
    __bf16* __restrict__ Qh, __bf16* __restrict__ Ql,
    __bf16* __restrict__ Kh, __bf16* __restrict__ Kl,
    __bf16* __restrict__ Vt)
{
  // xh:[0,16384) xl:[16384,32768) wt_h:[32768,40960) wt_l:[40960,49152)
  // vtmp (bf16 [64][132]) aliases wt: [32768, 49664)
  __shared__ __align__(16) unsigned char sm[49664];
  const int tid = threadIdx.x;
  const int lane = tid & 63, wv = tid >> 6;
  const int l15 = lane & 15, g = lane >> 4;
  const int b = blockIdx.y;
  const int n0 = blockIdx.x * 64;
  const f32x4 Z4 = {0.f, 0.f, 0.f, 0.f};

  // stage x tile transposed -> xt[n][c], split hi/lo
  #pragma unroll 4
  for (int i = 0; i < 32; ++i) {
    int e = i * 256 + tid;
    int nl = e & 63, c = e >> 6;
    float f = x[((size_t)(b * CD + c)) * NN + n0 + nl];
    __bf16 h = (__bf16)f;
    __bf16 lo = (__bf16)(f - (float)h);
    unsigned off = swz256((unsigned)nl, (unsigned)(c * 2));
    *(__bf16*)(sm + off) = h;
    *(__bf16*)(sm + 16384 + off) = lo;
  }
  __syncthreads();

  // hoist A fragments (this wave's 16 rows, full K=128)
  bf16x8 ah[4], al[4];
  #pragma unroll
  for (int kk = 0; kk < 4; ++kk) {
    unsigned off = swz256((unsigned)(wv * 16 + l15), (unsigned)(kk * 64 + g * 16));
    ah[kk] = *(const bf16x8*)(sm + off);
    al[kk] = *(const bf16x8*)(sm + 16384 + off);
  }

  // Q then K, split precision, quarter tiles of douts (32 at a time)
  for (int mat = 0; mat < 2; ++mat) {
    const float* gw = mat ? kw : qw;
    const float* gb = mat ? kb : qb;
    __bf16* Oh = mat ? Kh : Qh;
    __bf16* Ol = mat ? Kl : Ql;
    const float sc = mat ? 1.0f : SCALE;
    for (int qd = 0; qd < 4; ++qd) {
      #pragma unroll 4
      for (int i = 0; i < 16; ++i) {  // stage wT quarter [32 dout][128 c] hi/lo
        int e = i * 256 + tid;
        int dl = e & 31, c = e >> 5;
        float f = gw[c * CD + qd * 32 + dl];
        __bf16 h = (__bf16)f;
        __bf16 lo = (__bf16)(f - (float)h);
        unsigned off = swz256((unsigned)dl, (unsigned)(c * 2));
        *(__bf16*)(sm + 32768 + off) = h;
        *(__bf16*)(sm + 40960 + off) = lo;
      }
      __syncthreads();
      #pragma unroll
      for (int fr = 0; fr < 2; ++fr) {
        f32x4 acc = Z4;
        #pragma unroll
        for (int kk = 0; kk < 4; ++kk) {
          unsigned off = swz256((unsigned)(fr * 16 + l15), (unsigned)(kk * 64 + g * 16));
          bf16x8 bh = *(const bf16x8*)(sm + 32768 + off);
          bf16x8 bl = *(const bf16x8*)(sm + 40960 + off);
          acc = __builtin_amdgcn_mfma_f32_16x16x32_bf16(ah[kk], bh, acc, 0, 0, 0);
          acc = __builtin_amdgcn_mfma_f32_16x16x32_bf16(ah[kk], bl, acc, 0, 0, 0);
          acc = __builtin_amdgcn_mfma_f32_16x16x32_bf16(al[kk], bh, acc, 0, 0, 0);
        }
        const int dout = qd * 32 + fr * 16 + l15;
        const float bias = gb[dout];
        #pragma unroll
        for (int r = 0; r < 4; ++r) {
          int row = n0 + wv * 16 + g * 4 + r;
          float v = (acc[r] + bias) * sc;
          __bf16 h = (__bf16)v;
          __bf16 lo = (__bf16)(v - (float)h);
          size_t go = ((size_t)(b * NN + row)) * CD + dout;
          Oh[go] = h;
          Ol[go] = lo;
        }
      }
      __syncthreads();
    }
  }

  // V: plain bf16, accumulate all 128 douts, then transpose out via LDS
  f32x4 accV[8];
  #pragma unroll
  for (int i = 0; i < 8; ++i) accV[i] = Z4;
  for (int qd = 0; qd < 4; ++qd) {
    #pragma unroll 4
    for (int i = 0; i < 16; ++i) {
      int e = i * 256 + tid;
      int dl = e & 31, c = e >> 5;
      float f = vw[c * CD + qd * 32 + dl];
      *(__bf16*)(sm + 32768 + swz256((unsigned)dl, (unsigned)(c * 2))) = (__bf16)f;
    }
    __syncthreads();
    #pragma unroll
    for (int fr = 0; fr < 2; ++fr) {
      f32x4 acc = accV[qd * 2 + fr];
      #pragma unroll
      for (int kk = 0; kk < 4; ++kk) {
        unsigned off = swz256((unsigned)(fr * 16 + l15), (unsigned)(kk * 64 + g * 16));
        bf16x8 bh = *(const bf16x8*)(sm + 32768 + off);
        acc = __builtin_amdgcn_mfma_f32_16x16x32_bf16(ah[kk], bh, acc, 0, 0, 0);
      }
      accV[qd * 2 + fr] = acc;
    }
    __syncthreads();
  }
  // write V tile to vtmp[64][132] bf16 (aliases wt region; sync'd above)
  #pragma unroll
  for (int df = 0; df < 8; ++df) {
    int dout = df * 16 + l15;
    float bias = vb[dout];
    #pragma unroll
    for (int r = 0; r < 4; ++r) {
      int row = wv * 16 + g * 4 + r;
      *(__bf16*)(sm + 32768 + (row * 132 + dout) * 2) = (__bf16)(accV[df][r] + bias);
    }
  }
  __syncthreads();
  #pragma unroll 4
  for (int i = 0; i < 32; ++i) {
    int e = i * 256 + tid;
    int nl = e & 63, dout = e >> 6;
    __bf16 v = *(const __bf16*)(sm + 32768 + (nl * 132 + dout) * 2);
    Vt[((size_t)(b * CD + dout)) * NN + n0 + nl] = v;
  }
}

// ---------------------------------------------------------------------------
// Kernel 2: flash attention (64 q-rows/block, KV tiles of 64) + fused
//  output projection + bias + residual.  QK^T in split bf16 (3 MFMAs).
//  v2: T14 async prefetch, defer-rescale, setprio around MFMA clusters.
// ---------------------------------------------------------------------------
__global__ __launch_bounds__(256, 2) void attn_kernel(
    const __bf16* __restrict__ Qh, const __bf16* __restrict__ Ql,
    const __bf16* __restrict__ Kh, const __bf16* __restrict__ Kl,
    const __bf16* __restrict__ Vt, const float* __restrict__ x,
    const float* __restrict__ pw, const float* __restrict__ pb,
    float* __restrict__ out)
{
  // loop:     KH:[0,16384) KL:[16384,32768) VT:[32768,49152) P:[49152,57344)
  // epilogue: O:[0,16384)  PWT:[16384,49152)   (aliases loop bufs after sync)
  __shared__ __align__(16) unsigned char sm[57344];
  const int tid = threadIdx.x;
  const int lane = tid & 63, wv = tid >> 6;
  const int l15 = lane & 15, g = lane >> 4;
  const int b = blockIdx.y;
  const int q0 = blockIdx.x * 64;
  const f32x4 Z4 = {0.f, 0.f, 0.f, 0.f};

  // Q fragments (hi/lo) straight from global into registers
  bf16x8 qh[4], ql[4];
  #pragma unroll
  for (int kk = 0; kk < 4; ++kk) {
    size_t off = ((size_t)(b * NN + q0 + wv * 16 + l15)) * CD + kk * 32 + g * 8;
    qh[kk] = *(const bf16x8*)(Qh + off);
    ql[kk] = *(const bf16x8*)(Ql + off);
  }

  f32x4 accO[8];
  #pragma unroll
  for (int i = 0; i < 8; ++i) accO[i] = Z4;
  float mrow[4], lrow[4];
  #pragma unroll
  for (int r = 0; r < 4; ++r) { mrow[r] = -__builtin_inff(); lrow[r] = 0.f; }

  // T14 prefetch registers + address precompute
  bf16x8 pkh[4], pkl[4], pvv[4];
  const int rK = tid >> 4, sK = tid & 15;   // K tiles: rows rK + i*16
  const int rV = tid >> 3, sV = tid & 7;    // V tile:  rows rV + i*32

  #define ISSUE_TILE(KT)                                                        \
    {                                                                           \
      const size_t kb_ = (size_t)(b * NN + (KT) * 64);                          \
      _Pragma("unroll")                                                         \
      for (int i = 0; i < 4; ++i) {                                             \
        pkh[i] = *(const bf16x8*)(Kh + (kb_ + i * 16 + rK) * CD + sK * 8);      \
        pkl[i] = *(const bf16x8*)(Kl + (kb_ + i * 16 + rK) * CD + sK * 8);      \
        pvv[i] = *(const bf16x8*)(Vt + ((size_t)(b * CD) + i * 32 + rV) * NN +  \
                                  (KT) * 64 + sV * 8);                          \
      }                                                                         \
    }
  #define COMMIT_TILE()                                                         \
    {                                                                           \
      _Pragma("unroll")                                                         \
      for (int i = 0; i < 4; ++i) {                                             \
        unsigned o_ = swz256((unsigned)(i * 16 + rK), (unsigned)(sK * 16));     \
        *(bf16x8*)(sm + o_) = pkh[i];                                           \
        *(bf16x8*)(sm + 16384 + o_) = pkl[i];                                   \
        *(bf16x8*)(sm + 32768 +                                                 \
                   swz128((unsigned)(i * 32 + rV), (unsigned)(sV * 16))) = pvv[i]; \
      }                                                                         \
    }

  ISSUE_TILE(0);
  COMMIT_TILE();
  __syncthreads();

  for (int kt = 0; kt < 64; ++kt) {
    if (kt < 63) ISSUE_TILE(kt + 1);   // latency hides under this tile's compute

    // S = Qs * K^T  (split: hh + hl + lh)
    f32x4 s4[4];
    #pragma unroll
    for (int kf = 0; kf < 4; ++kf) s4[kf] = Z4;
    __builtin_amdgcn_s_setprio(1);
    #pragma unroll
    for (int kf = 0; kf < 4; ++kf) {
      #pragma unroll
      for (int kk = 0; kk < 4; ++kk) {
        unsigned off = swz256((unsigned)(kf * 16 + l15), (unsigned)(kk * 64 + g * 16));
        bf16x8 bh = *(const bf16x8*)(sm + off);
        bf16x8 bl = *(const bf16x8*)(sm + 16384 + off);
        s4[kf] = __builtin_amdgcn_mfma_f32_16x16x32_bf16(qh[kk], bh, s4[kf], 0, 0, 0);
        s4[kf] = __builtin_amdgcn_mfma_f32_16x16x32_bf16(qh[kk], bl, s4[kf], 0, 0, 0);
        s4[kf] = __builtin_amdgcn_mfma_f32_16x16x32_bf16(ql[kk], bh, s4[kf], 0, 0, 0);
      }
    }
    __builtin_amdgcn_s_setprio(0);

    // online softmax; mnew kept separate from mrow so alpha is computable in
    // the (rare) rescale branch only.
    float ps[4], mnew[4];
    bool grow = false;
    #pragma unroll
    for (int r = 0; r < 4; ++r) {
      float mx = fmaxf(fmaxf(s4[0][r], s4[1][r]), fmaxf(s4[2][r], s4[3][r]));
      mx = fmaxf(mx, __shfl_xor(mx, 1));
      mx = fmaxf(mx, __shfl_xor(mx, 2));
      mx = fmaxf(mx, __shfl_xor(mx, 4));
      mx = fmaxf(mx, __shfl_xor(mx, 8));
      float mn = fmaxf(mrow[r], mx);
      mnew[r] = mn;
      grow = grow || (mn > mrow[r]);
      float p0 = 0.f;
      #pragma unroll
      for (int kf = 0; kf < 4; ++kf) {
        float p = exp2f((s4[kf][r] - mn) * L2E);
        s4[kf][r] = p;
        p0 += p;
      }
      p0 += __shfl_xor(p0, 1);
      p0 += __shfl_xor(p0, 2);
      p0 += __shfl_xor(p0, 4);
      p0 += __shfl_xor(p0, 8);
      ps[r] = p0;
    }
    if (__any((int)grow)) {          // defer-rescale: usually skipped
      #pragma unroll
      for (int r = 0; r < 4; ++r) {
        float alpha = exp2f((mrow[r] - mnew[r]) * L2E);
        lrow[r] *= alpha;
        #pragma unroll
        for (int df = 0; df < 8; ++df) accO[df][r] *= alpha;
      }
    }
    #pragma unroll
    for (int r = 0; r < 4; ++r) { mrow[r] = mnew[r]; lrow[r] += ps[r]; }

    // write P (bf16) to this wave's private LDS rows (wave-local, no barrier)
    #pragma unroll
    for (int kf = 0; kf < 4; ++kf) {
      #pragma unroll
      for (int r = 0; r < 4; ++r) {
        unsigned row = (unsigned)(wv * 16 + g * 4 + r);
        *(__bf16*)(sm + 49152 + swz128(row, (unsigned)((kf * 16 + l15) * 2))) =
            (__bf16)s4[kf][r];
      }
    }

    // O += P * V
    bf16x8 pa[2];
    #pragma unroll
    for (int kk2 = 0; kk2 < 2; ++kk2)
      pa[kk2] = *(const bf16x8*)(sm + 49152 +
                  swz128((unsigned)(wv * 16 + l15), (unsigned)(kk2 * 64 + g * 16)));
    __builtin_amdgcn_s_setprio(1);
    #pragma unroll
    for (int df = 0; df < 8; ++df) {
      #pragma unroll
      for (int kk2 = 0; kk2 < 2; ++kk2) {
        bf16x8 bv = *(const bf16x8*)(sm + 32768 +
                      swz128((unsigned)(df * 16 + l15), (unsigned)(kk2 * 64 + g * 16)));
        accO[df] = __builtin_amdgcn_mfma_f32_16x16x32_bf16(pa[kk2], bv, accO[df], 0, 0, 0);
      }
    }
    __builtin_amdgcn_s_setprio(0);

    __syncthreads();                  // all waves done reading K/V of tile kt
    if (kt < 63) COMMIT_TILE();       // vmcnt wait auto-inserted here
    __syncthreads();
  }
  #undef ISSUE_TILE
  #undef COMMIT_TILE

  // epilogue: O/l -> bf16 LDS, stage proj_w^T, hout = O @ pw + pb + residual
  float rl[4];
  #pragma unroll
  for (int r = 0; r < 4; ++r) rl[r] = 1.0f / lrow[r];
  #pragma unroll
  for (int df = 0; df < 8; ++df) {
    #pragma unroll
    for (int r = 0; r < 4; ++r) {
      unsigned row = (unsigned)(wv * 16 + g * 4 + r);
      *(__bf16*)(sm + swz256(row, (unsigned)((df * 16 + l15) * 2))) =
          (__bf16)(accO[df][r] * rl[r]);
    }
  }
  #pragma unroll 4
  for (int i = 0; i < 16; ++i) {  // pwT[dout][c] bf16 at 16384
    int e = i * 256 + tid;
    int c = e >> 5, d4 = e & 31;
    const float4 w4 = *(const float4*)(pw + c * CD + d4 * 4);
    *(__bf16*)(sm + 16384 + swz256((unsigned)(d4 * 4 + 0), (unsigned)(c * 2))) = (__bf16)w4.x;
    *(__bf16*)(sm + 16384 + swz256((unsigned)(d4 * 4 + 1), (unsigned)(c * 2))) = (__bf16)w4.y;
    *(__bf16*)(sm + 16384 + swz256((unsigned)(d4 * 4 + 2), (unsigned)(c * 2))) = (__bf16)w4.z;
    *(__bf16*)(sm + 16384 + swz256((unsigned)(d4 * 4 + 3), (unsigned)(c * 2))) = (__bf16)w4.w;
  }
  __syncthreads();

  bf16x8 oa[4];
  #pragma unroll
  for (int kk = 0; kk < 4; ++kk)
    oa[kk] = *(const bf16x8*)(sm + swz256((unsigned)(wv * 16 + l15),
                                          (unsigned)(kk * 64 + g * 16)));
  #pragma unroll
  for (int df = 0; df < 8; ++df) {
    f32x4 acc = Z4;
    #pragma unroll
    for (int kk = 0; kk < 4; ++kk) {
      bf16x8 bw = *(const bf16x8*)(sm + 16384 +
                    swz256((unsigned)(df * 16 + l15), (unsigned)(kk * 64 + g * 16)));
      acc = __builtin_amdgcn_mfma_f32_16x16x32_bf16(oa[kk], bw, acc, 0, 0, 0);
    }
    const int cc = df * 16 + l15;
    const float bias = pb[cc];
    #pragma unroll
    for (int r = 0; r < 4; ++r) {
      int row = q0 + wv * 16 + g * 4 + r;
      float val = acc[r] + bias + x[((size_t)(b * CD + cc)) * NN + row];
      out[((size_t)(b * NN + row)) * CD + cc] = val;
    }
  }
}

// ---------------------------------------------------------------------------
extern "C" void kernel_launch(void* const* d_in, const int* in_sizes, int n_in,
                              void* d_out, int out_size, void* d_ws, size_t ws_size,
                              hipStream_t stream) {
  (void)in_sizes; (void)n_in; (void)out_size; (void)ws_size;
  const float* x  = (const float*)d_in[0];
  const float* qw = (const float*)d_in[1];
  const float* qb = (const float*)d_in[2];
  const float* kw = (const float*)d_in[3];
  const float* kb = (const float*)d_in[4];
  const float* vw = (const float*)d_in[5];
  const float* vb = (const float*)d_in[6];
  const float* pw = (const float*)d_in[7];
  const float* pb = (const float*)d_in[8];
  float* out = (float*)d_out;

  const size_t SZ = (size_t)NB * NN * CD;  // 4.19M elems per buffer
  __bf16* Qh = (__bf16*)d_ws;              // ws usage: 5 * 8.39 MB = 41.9 MB
  __bf16* Ql = Qh + SZ;
  __bf16* Kh = Ql + SZ;
  __bf16* Kl = Kh + SZ;
  __bf16* Vt = Kl + SZ;

  dim3 grid(NN / 64, NB), blk(256);
  qkv_kernel<<<grid, blk, 0, stream>>>(x, qw, qb, kw, kb, vw, vb,
                                       Qh, Ql, Kh, Kl, Vt);
  attn_kernel<<<grid, blk, 0, stream>>>(Qh, Ql, Kh, Kl, Vt, x, pw, pb, out);
}

// Round 5
// 300.385 us; speedup vs baseline: 1.1697x; 1.1473x over previous
//
#include <hip/hip_runtime.h>

// B=8, C=d=128, H=W=64, N=H*W=4096
#define NB 8
#define CD 128
#define NN 4096
#define SCALE 0.08838834764831845f
#define L2E 1.44269504088896f
#define QSCALE (SCALE * L2E)   // fold softmax scale AND log2(e) into Q

typedef __bf16 bf16x8 __attribute__((ext_vector_type(8)));
typedef float f32x4 __attribute__((ext_vector_type(4)));

// XOR swizzles on 16B blocks within a row; involution -> same fn for write & read.
__device__ __forceinline__ unsigned swz256(unsigned row, unsigned b) {
  unsigned s = b >> 4, o = b & 15u;
  unsigned sw = (s & 8u) | ((s & 7u) ^ (row & 7u));
  return row * 256u + sw * 16u + o;
}
__device__ __forceinline__ unsigned swz128(unsigned row, unsigned b) {
  unsigned s = b >> 4, o = b & 15u;
  unsigned sw = (s ^ row) & 7u;
  return row * 128u + sw * 16u + o;
}
// P-buffer swizzle: conflict-free for BOTH the scalar write pattern
// (rows wv*16+g*4+r, cols kf*16+l15) and the b128 read (rows wv*16+l15).
__device__ __forceinline__ unsigned swzP(unsigned row, unsigned b) {
  unsigned s = b >> 4, o = b & 15u;
  unsigned sw = (s ^ (row ^ (row >> 2))) & 7u;
  return row * 128u + sw * 16u + o;
}

// DPP rotate-within-16 (VALU pipe, no LDS) for the row-max butterfly.
#define DPP_ROR_F(x, N)                                                       \
  __builtin_bit_cast(float, __builtin_amdgcn_update_dpp(                      \
      __builtin_bit_cast(int, (x)), __builtin_bit_cast(int, (x)),             \
      0x120 + (N), 0xF, 0xF, false))

// ---------------------------------------------------------------------------
// Kernel 1: fused transpose + QKV projection.
//  Q,K computed in split bf16 (3 MFMAs: hh+hl+lh) for ~fp32 logit accuracy.
//  Q carries SCALE*log2(e).  Grid is 1-D; batch = bid&7 -> XCD affinity.
// ---------------------------------------------------------------------------
__global__ __launch_bounds__(256, 2) void qkv_kernel(
    const float* __restrict__ x,
    const float* __restrict__ qw, const float* __restrict__ qb,
    const float* __restrict__ kw, const float* __restrict__ kb,
    const float* __restrict__ vw, const float* __restrict__ vb,
    __bf16* __restrict__ Qh, __bf16* __restrict__ Ql,
    __bf16* __restrict__ Kh, __bf16* __restrict__ Kl,
    __bf16* __restrict__ Vt)
{
  // xh:[0,16384) xl:[16384,32768) wt_h:[32768,40960) wt_l:[40960,49152)
  // vtmp (bf16 [64][132]) aliases wt: [32768, 49664)
  __shared__ __align__(16) unsigned char sm[49664];
  const int tid = threadIdx.x;
  const int lane = tid & 63, wv = tid >> 6;
  const int l15 = lane & 15, g = lane >> 4;
  const int b = blockIdx.x & 7;           // batch -> XCD (round-robin dispatch)
  const int n0 = (blockIdx.x >> 3) * 64;
  const f32x4 Z4 = {0.f, 0.f, 0.f, 0.f};

  // stage x tile transposed -> xt[n][c], split hi/lo
  #pragma unroll 4
  for (int i = 0; i < 32; ++i) {
    int e = i * 256 + tid;
    int nl = e & 63, c = e >> 6;
    float f = x[((size_t)(b * CD + c)) * NN + n0 + nl];
    __bf16 h = (__bf16)f;
    __bf16 lo = (__bf16)(f - (float)h);
    unsigned off = swz256((unsigned)nl, (unsigned)(c * 2));
    *(__bf16*)(sm + off) = h;
    *(__bf16*)(sm + 16384 + off) = lo;
  }
  __syncthreads();

  // hoist A fragments (this wave's 16 rows, full K=128)
  bf16x8 ah[4], al[4];
  #pragma unroll
  for (int kk = 0; kk < 4; ++kk) {
    unsigned off = swz256((unsigned)(wv * 16 + l15), (unsigned)(kk * 64 + g * 16));
    ah[kk] = *(const bf16x8*)(sm + off);
    al[kk] = *(const bf16x8*)(sm + 16384 + off);
  }

  // Q then K, split precision, quarter tiles of douts (32 at a time)
  for (int mat = 0; mat < 2; ++mat) {
    const float* gw = mat ? kw : qw;
    const float* gb = mat ? kb : qb;
    __bf16* Oh = mat ? Kh : Qh;
    __bf16* Ol = mat ? Kl : Ql;
    const float sc = mat ? 1.0f : QSCALE;
    for (int qd = 0; qd < 4; ++qd) {
      #pragma unroll 4
      for (int i = 0; i < 16; ++i) {  // stage wT quarter [32 dout][128 c] hi/lo
        int e = i * 256 + tid;
        int dl = e & 31, c = e >> 5;
        float f = gw[c * CD + qd * 32 + dl];
        __bf16 h = (__bf16)f;
        __bf16 lo = (__bf16)(f - (float)h);
        unsigned off = swz256((unsigned)dl, (unsigned)(c * 2));
        *(__bf16*)(sm + 32768 + off) = h;
        *(__bf16*)(sm + 40960 + off) = lo;
      }
      __syncthreads();
      #pragma unroll
      for (int fr = 0; fr < 2; ++fr) {
        f32x4 acc = Z4;
        #pragma unroll
        for (int kk = 0; kk < 4; ++kk) {
          unsigned off = swz256((unsigned)(fr * 16 + l15), (unsigned)(kk * 64 + g * 16));
          bf16x8 bh = *(const bf16x8*)(sm + 32768 + off);
          bf16x8 bl = *(const bf16x8*)(sm + 40960 + off);
          acc = __builtin_amdgcn_mfma_f32_16x16x32_bf16(ah[kk], bh, acc, 0, 0, 0);
          acc = __builtin_amdgcn_mfma_f32_16x16x32_bf16(ah[kk], bl, acc, 0, 0, 0);
          acc = __builtin_amdgcn_mfma_f32_16x16x32_bf16(al[kk], bh, acc, 0, 0, 0);
        }
        const int dout = qd * 32 + fr * 16 + l15;
        const float bias = gb[dout];
        #pragma unroll
        for (int r = 0; r < 4; ++r) {
          int row = n0 + wv * 16 + g * 4 + r;
          float v = (acc[r] + bias) * sc;
          __bf16 h = (__bf16)v;
          __bf16 lo = (__bf16)(v - (float)h);
          size_t go = ((size_t)(b * NN + row)) * CD + dout;
          Oh[go] = h;
          Ol[go] = lo;
        }
      }
      __syncthreads();
    }
  }

  // V: plain bf16, accumulate all 128 douts, then transpose out via LDS
  f32x4 accV[8];
  #pragma unroll
  for (int i = 0; i < 8; ++i) accV[i] = Z4;
  for (int qd = 0; qd < 4; ++qd) {
    #pragma unroll 4
    for (int i = 0; i < 16; ++i) {
      int e = i * 256 + tid;
      int dl = e & 31, c = e >> 5;
      float f = vw[c * CD + qd * 32 + dl];
      *(__bf16*)(sm + 32768 + swz256((unsigned)dl, (unsigned)(c * 2))) = (__bf16)f;
    }
    __syncthreads();
    #pragma unroll
    for (int fr = 0; fr < 2; ++fr) {
      f32x4 acc = accV[qd * 2 + fr];
      #pragma unroll
      for (int kk = 0; kk < 4; ++kk) {
        unsigned off = swz256((unsigned)(fr * 16 + l15), (unsigned)(kk * 64 + g * 16));
        bf16x8 bh = *(const bf16x8*)(sm + 32768 + off);
        acc = __builtin_amdgcn_mfma_f32_16x16x32_bf16(ah[kk], bh, acc, 0, 0, 0);
      }
      accV[qd * 2 + fr] = acc;
    }
    __syncthreads();
  }
  // write V tile to vtmp[64][132] bf16 (aliases wt region; sync'd above)
  #pragma unroll
  for (int df = 0; df < 8; ++df) {
    int dout = df * 16 + l15;
    float bias = vb[dout];
    #pragma unroll
    for (int r = 0; r < 4; ++r) {
      int row = wv * 16 + g * 4 + r;
      *(__bf16*)(sm + 32768 + (row * 132 + dout) * 2) = (__bf16)(accV[df][r] + bias);
    }
  }
  __syncthreads();
  #pragma unroll 4
  for (int i = 0; i < 32; ++i) {
    int e = i * 256 + tid;
    int nl = e & 63, dout = e >> 6;
    __bf16 v = *(const __bf16*)(sm + 32768 + (nl * 132 + dout) * 2);
    Vt[((size_t)(b * CD + dout)) * NN + n0 + nl] = v;
  }
}

// ---------------------------------------------------------------------------
// Kernel 2: flash attention (64 q-rows/block, KV tiles of 64) + fused
//  output projection + bias + residual.  QK^T in split bf16 (3 MFMAs).
//  v3: XCD batch affinity, DPP row-max, row-sum via ones-column MFMA,
//      conflict-free P swizzle, log2-domain softmax, pinned prefetch.
// ---------------------------------------------------------------------------
__global__ __launch_bounds__(256, 2) void attn_kernel(
    const __bf16* __restrict__ Qh, const __bf16* __restrict__ Ql,
    const __bf16* __restrict__ Kh, const __bf16* __restrict__ Kl,
    const __bf16* __restrict__ Vt, const float* __restrict__ x,
    const float* __restrict__ pw, const float* __restrict__ pb,
    float* __restrict__ out)
{
  // loop:     KH:[0,16384) KL:[16384,32768) VT:[32768,49152) P:[49152,57344)
  // epilogue: O:[0,16384)  PWT:[16384,49152)   (aliases loop bufs after sync)
  __shared__ __align__(16) unsigned char sm[57344];
  const int tid = threadIdx.x;
  const int lane = tid & 63, wv = tid >> 6;
  const int l15 = lane & 15, g = lane >> 4;
  const int b = blockIdx.x & 7;           // batch -> XCD (round-robin dispatch)
  const int q0 = (blockIdx.x >> 3) * 64;
  const f32x4 Z4 = {0.f, 0.f, 0.f, 0.f};

  // Q fragments (hi/lo) straight from global into registers
  bf16x8 qh[4], ql[4];
  #pragma unroll
  for (int kk = 0; kk < 4; ++kk) {
    size_t off = ((size_t)(b * NN + q0 + wv * 16 + l15)) * CD + kk * 32 + g * 8;
    qh[kk] = *(const bf16x8*)(Qh + off);
    ql[kk] = *(const bf16x8*)(Ql + off);
  }

  // constant ones-column B fragment: col 0 of B = 1.0 along all k
  bf16x8 bones;
  {
    __bf16 v = (l15 == 0) ? (__bf16)1.0f : (__bf16)0.0f;
    #pragma unroll
    for (int j = 0; j < 8; ++j) bones[j] = v;
  }

  f32x4 accO[8];
  #pragma unroll
  for (int i = 0; i < 8; ++i) accO[i] = Z4;
  f32x4 accL = Z4;                 // row-sum accumulator (valid in l15==0 lanes)
  float mrow[4];
  #pragma unroll
  for (int r = 0; r < 4; ++r) mrow[r] = -__builtin_inff();

  // T14 prefetch registers + address precompute
  bf16x8 pkh[4], pkl[4], pvv[4];
  const int rK = tid >> 4, sK = tid & 15;   // K tiles: rows rK + i*16
  const int rV = tid >> 3, sV = tid & 7;    // V tile:  rows rV + i*32

  #define ISSUE_TILE(KT)                                                        \
    {                                                                           \
      const size_t kb_ = (size_t)(b * NN + (KT) * 64);                          \
      _Pragma("unroll")                                                         \
      for (int i = 0; i < 4; ++i) {                                             \
        pkh[i] = *(const bf16x8*)(Kh + (kb_ + i * 16 + rK) * CD + sK * 8);      \
        pkl[i] = *(const bf16x8*)(Kl + (kb_ + i * 16 + rK) * CD + sK * 8);      \
        pvv[i] = *(const bf16x8*)(Vt + ((size_t)(b * CD) + i * 32 + rV) * NN +  \
                                  (KT) * 64 + sV * 8);                          \
      }                                                                         \
    }
  #define COMMIT_TILE()                                                         \
    {                                                                           \
      _Pragma("unroll")                                                         \
      for (int i = 0; i < 4; ++i) {                                             \
        unsigned o_ = swz256((unsigned)(i * 16 + rK), (unsigned)(sK * 16));     \
        *(bf16x8*)(sm + o_) = pkh[i];                                           \
        *(bf16x8*)(sm + 16384 + o_) = pkl[i];                                   \
        *(bf16x8*)(sm + 32768 +                                                 \
                   swz128((unsigned)(i * 32 + rV), (unsigned)(sV * 16))) = pvv[i]; \
      }                                                                         \
    }

  ISSUE_TILE(0);
  COMMIT_TILE();
  __syncthreads();

  for (int kt = 0; kt < 64; ++kt) {
    if (kt < 63) ISSUE_TILE(kt + 1);   // latency hides under this tile's compute
    __builtin_amdgcn_sched_barrier(0); // pin load issue before the MFMA cluster

    // S = Qs * K^T  (split: hh + hl + lh), logits already in log2 domain
    f32x4 s4[4];
    #pragma unroll
    for (int kf = 0; kf < 4; ++kf) s4[kf] = Z4;
    __builtin_amdgcn_s_setprio(1);
    #pragma unroll
    for (int kf = 0; kf < 4; ++kf) {
      #pragma unroll
      for (int kk = 0; kk < 4; ++kk) {
        unsigned off = swz256((unsigned)(kf * 16 + l15), (unsigned)(kk * 64 + g * 16));
        bf16x8 bh = *(const bf16x8*)(sm + off);
        bf16x8 bl = *(const bf16x8*)(sm + 16384 + off);
        s4[kf] = __builtin_amdgcn_mfma_f32_16x16x32_bf16(qh[kk], bh, s4[kf], 0, 0, 0);
        s4[kf] = __builtin_amdgcn_mfma_f32_16x16x32_bf16(qh[kk], bl, s4[kf], 0, 0, 0);
        s4[kf] = __builtin_amdgcn_mfma_f32_16x16x32_bf16(ql[kk], bh, s4[kf], 0, 0, 0);
      }
    }
    __builtin_amdgcn_s_setprio(0);

    // online softmax: row-max via DPP rotations (VALU pipe, no LDS);
    // row-sum comes from the ones-column MFMA below.
    float mnew[4];
    bool grow = false;
    #pragma unroll
    for (int r = 0; r < 4; ++r) {
      float mx = fmaxf(fmaxf(s4[0][r], s4[1][r]), fmaxf(s4[2][r], s4[3][r]));
      mx = fmaxf(mx, DPP_ROR_F(mx, 8));
      mx = fmaxf(mx, DPP_ROR_F(mx, 4));
      mx = fmaxf(mx, DPP_ROR_F(mx, 2));
      mx = fmaxf(mx, DPP_ROR_F(mx, 1));
      float mn = fmaxf(mrow[r], mx);
      mnew[r] = mn;
      grow = grow || (mn > mrow[r]);
      #pragma unroll
      for (int kf = 0; kf < 4; ++kf)
        s4[kf][r] = exp2f(s4[kf][r] - mn);
    }
    if (__any((int)grow)) {          // defer-rescale: usually skipped
      #pragma unroll
      for (int r = 0; r < 4; ++r) {
        float alpha = exp2f(mrow[r] - mnew[r]);
        accL[r] *= alpha;
        #pragma unroll
        for (int df = 0; df < 8; ++df) accO[df][r] *= alpha;
      }
    }
    #pragma unroll
    for (int r = 0; r < 4; ++r) mrow[r] = mnew[r];

    // write P (bf16) to this wave's private LDS rows (wave-local, no barrier)
    #pragma unroll
    for (int kf = 0; kf < 4; ++kf) {
      #pragma unroll
      for (int r = 0; r < 4; ++r) {
        unsigned row = (unsigned)(wv * 16 + g * 4 + r);
        *(__bf16*)(sm + 49152 + swzP(row, (unsigned)((kf * 16 + l15) * 2))) =
            (__bf16)s4[kf][r];
      }
    }

    // O += P * V ; row-sum l += P * ones (denominator matches bf16 P exactly)
    bf16x8 pa[2];
    #pragma unroll
    for (int kk2 = 0; kk2 < 2; ++kk2)
      pa[kk2] = *(const bf16x8*)(sm + 49152 +
                  swzP((unsigned)(wv * 16 + l15), (unsigned)(kk2 * 64 + g * 16)));
    __builtin_amdgcn_s_setprio(1);
    accL = __builtin_amdgcn_mfma_f32_16x16x32_bf16(pa[0], bones, accL, 0, 0, 0);
    accL = __builtin_amdgcn_mfma_f32_16x16x32_bf16(pa[1], bones, accL, 0, 0, 0);
    #pragma unroll
    for (int df = 0; df < 8; ++df) {
      #pragma unroll
      for (int kk2 = 0; kk2 < 2; ++kk2) {
        bf16x8 bv = *(const bf16x8*)(sm + 32768 +
                      swz128((unsigned)(df * 16 + l15), (unsigned)(kk2 * 64 + g * 16)));
        accO[df] = __builtin_amdgcn_mfma_f32_16x16x32_bf16(pa[kk2], bv, accO[df], 0, 0, 0);
      }
    }
    __builtin_amdgcn_s_setprio(0);

    __syncthreads();                  // all waves done reading K/V of tile kt
    if (kt < 63) COMMIT_TILE();       // vmcnt wait auto-inserted here
    __syncthreads();
  }
  #undef ISSUE_TILE
  #undef COMMIT_TILE

  // epilogue: broadcast row-sums from l15==0 lanes, O/l -> bf16 LDS,
  // stage proj_w^T, hout = O @ pw + pb + residual
  float rl[4];
  #pragma unroll
  for (int r = 0; r < 4; ++r) {
    float lv = __shfl(accL[r], lane & 48);   // value from this group's l15==0 lane
    rl[r] = 1.0f / lv;
  }
  #pragma unroll
  for (int df = 0; df < 8; ++df) {
    #pragma unroll
    for (int r = 0; r < 4; ++r) {
      unsigned row = (unsigned)(wv * 16 + g * 4 + r);
      *(__bf16*)(sm + swz256(row, (unsigned)((df * 16 + l15) * 2))) =
          (__bf16)(accO[df][r] * rl[r]);
    }
  }
  #pragma unroll 4
  for (int i = 0; i < 16; ++i) {  // pwT[dout][c] bf16 at 16384
    int e = i * 256 + tid;
    int c = e >> 5, d4 = e & 31;
    const float4 w4 = *(const float4*)(pw + c * CD + d4 * 4);
    *(__bf16*)(sm + 16384 + swz256((unsigned)(d4 * 4 + 0), (unsigned)(c * 2))) = (__bf16)w4.x;
    *(__bf16*)(sm + 16384 + swz256((unsigned)(d4 * 4 + 1), (unsigned)(c * 2))) = (__bf16)w4.y;
    *(__bf16*)(sm + 16384 + swz256((unsigned)(d4 * 4 + 2), (unsigned)(c * 2))) = (__bf16)w4.z;
    *(__bf16*)(sm + 16384 + swz256((unsigned)(d4 * 4 + 3), (unsigned)(c * 2))) = (__bf16)w4.w;
  }
  __syncthreads();

  bf16x8 oa[4];
  #pragma unroll
  for (int kk = 0; kk < 4; ++kk)
    oa[kk] = *(const bf16x8*)(sm + swz256((unsigned)(wv * 16 + l15),
                                          (unsigned)(kk * 64 + g * 16)));
  #pragma unroll
  for (int df = 0; df < 8; ++df) {
    f32x4 acc = Z4;
    #pragma unroll
    for (int kk = 0; kk < 4; ++kk) {
      bf16x8 bw = *(const bf16x8*)(sm + 16384 +
                    swz256((unsigned)(df * 16 + l15), (unsigned)(kk * 64 + g * 16)));
      acc = __builtin_amdgcn_mfma_f32_16x16x32_bf16(oa[kk], bw, acc, 0, 0, 0);
    }
    const int cc = df * 16 + l15;
    const float bias = pb[cc];
    #pragma unroll
    for (int r = 0; r < 4; ++r) {
      int row = q0 + wv * 16 + g * 4 + r;
      float val = acc[r] + bias + x[((size_t)(b * CD + cc)) * NN + row];
      out[((size_t)(b * NN + row)) * CD + cc] = val;
    }
  }
}

// ---------------------------------------------------------------------------
extern "C" void kernel_launch(void* const* d_in, const int* in_sizes, int n_in,
                              void* d_out, int out_size, void* d_ws, size_t ws_size,
                              hipStream_t stream) {
  (void)in_sizes; (void)n_in; (void)out_size; (void)ws_size;
  const float* x  = (const float*)d_in[0];
  const float* qw = (const float*)d_in[1];
  const float* qb = (const float*)d_in[2];
  const float* kw = (const float*)d_in[3];
  const float* kb = (const float*)d_in[4];
  const float* vw = (const float*)d_in[5];
  const float* vb = (const float*)d_in[6];
  const float* pw = (const float*)d_in[7];
  const float* pb = (const float*)d_in[8];
  float* out = (float*)d_out;

  const size_t SZ = (size_t)NB * NN * CD;  // 4.19M elems per buffer
  __bf16* Qh = (__bf16*)d_ws;              // ws usage: 5 * 8.39 MB = 41.9 MB
  __bf16* Ql = Qh + SZ;
  __bf16* Kh = Ql + SZ;
  __bf16* Kl = Kh + SZ;
  __bf16* Vt = Kl + SZ;

  dim3 grid(512), blk(256);                // 1-D: bid&7 = batch = XCD
  qkv_kernel<<<grid, blk, 0, stream>>>(x, qw, qb, kw, kb, vw, vb,
                                       Qh, Ql, Kh, Kl, Vt);
  attn_kernel<<<grid, blk, 0, stream>>>(Qh, Ql, Kh, Kl, Vt, x, pw, pb, out);
}